// Round 3
// baseline (345.375 us; speedup 1.0000x reference)
//
#include <hip/hip_runtime.h>
#include <hip/hip_bf16.h>

typedef __attribute__((ext_vector_type(8))) short bf16x8;
typedef __attribute__((ext_vector_type(4))) float f32x4;

#define MFMA32(A,B,C) __builtin_amdgcn_mfma_f32_16x16x32_bf16(A,B,C,0,0,0)

__device__ __forceinline__ short f2bf(float f) {
    union { float f; unsigned u; } v; v.f = f;
    unsigned r = v.u + 0x7FFFu + ((v.u >> 16) & 1u);
    return (short)(r >> 16);
}

// One-time: transpose+convert weights to bf16.  wqkvT[768][256], wprojT[256][256]
__global__ void prep_weights(const float* __restrict__ wqkv,
                             const float* __restrict__ wproj,
                             short* __restrict__ wqkvT,
                             short* __restrict__ wprojT) {
    const int n = blockIdx.x, k = threadIdx.x;
    if (n < 768) wqkvT[n * 256 + k] = f2bf(wqkv[k * 768 + n]);
    else         wprojT[(n - 768) * 256 + k] = f2bf(wproj[k * 256 + (n - 768)]);
}

// swapped QKV pass: D[ch][token] = W . xw^T ; packed acc -> K=32 frag of [token][ch] (ch-halves
// in low/high 4 elems: ch c = h*16 + l4*4 + rg  <->  k' = l4*8 + h*4 + rg)
#define QK_PASS(WPTR, BOFF, SCALE, FOUT)                                                   \
  {                                                                                        \
    f32x4 acc[2][4];                                                                       \
    _Pragma("unroll") for (int h=0;h<2;++h)                                                \
      _Pragma("unroll") for (int t=0;t<4;++t) acc[h][t]=(f32x4){0.f,0.f,0.f,0.f};          \
    _Pragma("unroll") for (int kk=0;kk<8;++kk) {                                           \
      bf16x8 xf[4];                                                                        \
      _Pragma("unroll") for (int t=0;t<4;++t) {                                            \
        const int row = t*16 + l15;                                                        \
        xf[t] = *(const bf16x8*)(smem + row*512 + (((kk<<6)+(l4<<4)) ^ ((row&7)<<4)));     \
      }                                                                                    \
      _Pragma("unroll") for (int h=0;h<2;++h) {                                            \
        bf16x8 wf = *(const bf16x8*)((WPTR) + (h*16+l15)*256 + (kk<<5) + (l4<<3));         \
        _Pragma("unroll") for (int t=0;t<4;++t)                                            \
          acc[h][t] = MFMA32(wf, xf[t], acc[h][t]);                                        \
      }                                                                                    \
    }                                                                                      \
    _Pragma("unroll") for (int h=0;h<2;++h) {                                              \
      f32x4 bias = *(const f32x4*)(bqkv + (BOFF) + h*16 + (l4<<2));                        \
      _Pragma("unroll") for (int t=0;t<4;++t)                                              \
        _Pragma("unroll") for (int rg=0;rg<4;++rg)                                         \
          FOUT[t][h*4+rg] = f2bf((acc[h][t][rg] + bias[rg]) * (SCALE));                    \
    }                                                                                      \
  }

__launch_bounds__(512, 4)
__global__ void winattn_fused(const float* __restrict__ x,
                              const float* __restrict__ bqkv,
                              const float* __restrict__ bproj,
                              const short* __restrict__ wqkvT,
                              const short* __restrict__ wprojT,
                              float* __restrict__ out) {
    __shared__ char smem[65536];
    char* cbuf = smem + 32768;
    const int tid = threadIdx.x;
    const int wid = blockIdx.x;
    const int b  = wid >> 6;
    const int wh = (wid >> 3) & 7;
    const int ww = wid & 7;

    // ---------- Phase 1: stage rolled window -> LDS bf16 [64 rows][512B], XOR-swizzled ----------
    {
        const int r  = tid >> 3;
        const int cb = (tid & 7) << 5;
        if (r < 49) {
            const int i = r / 7, j = r - i * 7;
            int h  = wh * 7 + i + 3; if (h  >= 56) h  -= 56;
            int wc = ww * 7 + j + 3; if (wc >= 56) wc -= 56;
            const float* src = x + (((size_t)(b * 56 + h)) * 56 + wc) * 256 + cb;
            #pragma unroll
            for (int c = 0; c < 4; ++c) {
                f32x4 f0 = *(const f32x4*)(src + c * 8);
                f32x4 f1 = *(const f32x4*)(src + c * 8 + 4);
                bf16x8 o;
                #pragma unroll
                for (int q = 0; q < 4; ++q) { o[q] = f2bf(f0[q]); o[q + 4] = f2bf(f1[q]); }
                const int colbyte = (cb + c * 8) * 2;
                *(bf16x8*)(smem + r * 512 + (colbyte ^ ((r & 7) << 4))) = o;
            }
        } else {
            bf16x8 z;
            #pragma unroll
            for (int q = 0; q < 8; ++q) z[q] = 0;
            #pragma unroll
            for (int c = 0; c < 4; ++c) {
                const int colbyte = (cb + c * 8) * 2;
                *(bf16x8*)(smem + r * 512 + (colbyte ^ ((r & 7) << 4))) = z;
            }
        }
    }
    __syncthreads();

    const int wv  = tid >> 6;     // wave = head
    const int l   = tid & 63;
    const int l15 = l & 15;
    const int l4  = l >> 4;

    const short* wq  = wqkvT + ((wv << 5) << 8);
    const short* wk  = wq + (256 << 8);
    const short* wvv = wq + (512 << 8);

    // ---------- Phase 2a: q,k (swapped) — packed K=32 fragments, zero LDS round-trip ----------
    bf16x8 qp[4], kp[4];            // [token-tile], elems = packed ch (2 halves x 4)
    QK_PASS(wq, (wv << 5), 0.17677669529663687f, qp)
    QK_PASS(wk, 256 + (wv << 5), 1.0f, kp)

    // ---------- Phase 3a: S' = S^T = K.Q^T — 16 MFMA32, all in registers ----------
    f32x4 sS[4][4];                 // [kt-tile][q-tile]: D[kt][q], col=l15=q, row=l4*4+rg=kt
    #pragma unroll
    for (int t = 0; t < 4; ++t)
        #pragma unroll
        for (int qt = 0; qt < 4; ++qt) sS[t][qt] = (f32x4){0.f, 0.f, 0.f, 0.f};
    #pragma unroll
    for (int t = 0; t < 4; ++t)
        #pragma unroll
        for (int qt = 0; qt < 4; ++qt)
            sS[t][qt] = MFMA32(kp[t], qp[qt], sS[t][qt]);

    // ---------- Phase 3b: softmax over kt (per q-column = l15), packed P frags ----------
    bf16x8 pp[4][2];                // [q-tile][kt-tile-pair], elems: low4 = even tile, high4 = odd
    #pragma unroll
    for (int qt = 0; qt < 4; ++qt) {
        float ev[4][4];
        float m = -1e30f;
        #pragma unroll
        for (int t = 0; t < 4; ++t)
            #pragma unroll
            for (int rg = 0; rg < 4; ++rg) {
                const bool valid = (t < 3) || ((l4 | rg) == 0);   // kt < 49
                float v0 = valid ? sS[t][qt][rg] : -1e30f;
                ev[t][rg] = v0;
                m = fmaxf(m, v0);
            }
        m = fmaxf(m, __shfl_xor(m, 16));
        m = fmaxf(m, __shfl_xor(m, 32));
        float s = 0.f;
        #pragma unroll
        for (int t = 0; t < 4; ++t)
            #pragma unroll
            for (int rg = 0; rg < 4; ++rg) {
                float e = __expf(ev[t][rg] - m);   // masked entries underflow to 0
                ev[t][rg] = e;
                s += e;
            }
        s += __shfl_xor(s, 16);
        s += __shfl_xor(s, 32);
        const float inv = 1.f / s;
        #pragma unroll
        for (int t = 0; t < 4; ++t)
            #pragma unroll
            for (int rg = 0; rg < 4; ++rg)
                pp[qt][t >> 1][(t & 1) * 4 + rg] = f2bf(ev[t][rg] * inv);
    }

    // ---------- Phase 2b: v (unswapped) — packed V^T B-fragments directly ----------
    bf16x8 vp[2][2];                // [kt-tile-pair][ch-half]
    {
        f32x4 acc[4][2];
        #pragma unroll
        for (int t = 0; t < 4; ++t)
            #pragma unroll
            for (int h = 0; h < 2; ++h) acc[t][h] = (f32x4){0.f, 0.f, 0.f, 0.f};
        #pragma unroll
        for (int kk = 0; kk < 8; ++kk) {
            bf16x8 xf[4];
            #pragma unroll
            for (int t = 0; t < 4; ++t) {
                const int row = t * 16 + l15;
                xf[t] = *(const bf16x8*)(smem + row * 512 + (((kk << 6) + (l4 << 4)) ^ ((row & 7) << 4)));
            }
            #pragma unroll
            for (int h = 0; h < 2; ++h) {
                bf16x8 wf = *(const bf16x8*)(wvv + (h * 16 + l15) * 256 + (kk << 5) + (l4 << 3));
                #pragma unroll
                for (int t = 0; t < 4; ++t)
                    acc[t][h] = MFMA32(xf[t], wf, acc[t][h]);
            }
        }
        #pragma unroll
        for (int h = 0; h < 2; ++h) {
            const float bias = bqkv[512 + (wv << 5) + h * 16 + l15];
            #pragma unroll
            for (int t = 0; t < 4; ++t)
                #pragma unroll
                for (int rg = 0; rg < 4; ++rg)
                    vp[t >> 1][h][(t & 1) * 4 + rg] = f2bf(acc[t][h][rg] + bias);
        }
    }

    // ---------- Phase 3c: O = P.V — 16 MFMA32 ----------
    f32x4 o[4][2];                  // [q-tile][ch-half]
    #pragma unroll
    for (int qt = 0; qt < 4; ++qt)
        #pragma unroll
        for (int h = 0; h < 2; ++h) o[qt][h] = (f32x4){0.f, 0.f, 0.f, 0.f};
    #pragma unroll
    for (int tp = 0; tp < 2; ++tp)
        #pragma unroll
        for (int h = 0; h < 2; ++h)
            #pragma unroll
            for (int qt = 0; qt < 4; ++qt)
                o[qt][h] = MFMA32(pp[qt][tp], vp[tp][h], o[qt][h]);

    // heads concat -> cbuf (swizzled [64][512B])
    #pragma unroll
    for (int qt = 0; qt < 4; ++qt)
        #pragma unroll
        for (int h = 0; h < 2; ++h)
            #pragma unroll
            for (int rg = 0; rg < 4; ++rg) {
                const int row = qt * 16 + (l4 << 2) + rg;
                const int col = (wv << 5) + (h << 4) + l15;
                *(short*)(cbuf + row * 512 + ((col * 2) ^ ((row & 7) << 4))) = f2bf(o[qt][h][rg]);
            }
    __syncthreads();

    // ---------- Phase 4: proj GEMM + bias + scatter to un-rolled positions ----------
    f32x4 po[2][4];
    #pragma unroll
    for (int c = 0; c < 2; ++c)
        #pragma unroll
        for (int r = 0; r < 4; ++r) po[c][r] = (f32x4){0.f, 0.f, 0.f, 0.f};

    #pragma unroll
    for (int kk = 0; kk < 8; ++kk) {
        bf16x8 a[4];
        #pragma unroll
        for (int rt = 0; rt < 4; ++rt) {
            const int row = rt * 16 + l15;
            a[rt] = *(const bf16x8*)(cbuf + row * 512 + (((kk << 6) + (l4 << 4)) ^ ((row & 7) << 4)));
        }
        #pragma unroll
        for (int ct = 0; ct < 2; ++ct) {
            const short* bp = wprojT + (((wv << 5) + (ct << 4) + l15) << 8) + (kk << 5) + (l4 << 3);
            bf16x8 bfr = *(const bf16x8*)bp;
            #pragma unroll
            for (int rt = 0; rt < 4; ++rt)
                po[ct][rt] = MFMA32(a[rt], bfr, po[ct][rt]);
        }
    }

    #pragma unroll
    for (int ct = 0; ct < 2; ++ct) {
        const int col = (wv << 5) + (ct << 4) + l15;
        const float bias = bproj[col];
        #pragma unroll
        for (int rt = 0; rt < 4; ++rt) {
            #pragma unroll
            for (int rg = 0; rg < 4; ++rg) {
                const int row = rt * 16 + (l4 << 2) + rg;
                if (row < 49) {
                    const int i = row / 7, j = row - i * 7;
                    int h  = wh * 7 + i + 3; if (h  >= 56) h  -= 56;
                    int wc = ww * 7 + j + 3; if (wc >= 56) wc -= 56;
                    out[(((size_t)(b * 56 + h)) * 56 + wc) * 256 + col] = po[ct][rt][rg] + bias;
                }
            }
        }
    }
}

extern "C" void kernel_launch(void* const* d_in, const int* in_sizes, int n_in,
                              void* d_out, int out_size, void* d_ws, size_t ws_size,
                              hipStream_t stream) {
    const float* x     = (const float*)d_in[0];
    const float* wqkv  = (const float*)d_in[1];
    const float* bqkv  = (const float*)d_in[2];
    const float* wproj = (const float*)d_in[3];
    const float* bproj = (const float*)d_in[4];
    float* out = (float*)d_out;

    short* wqkvT  = (short*)d_ws;
    short* wprojT = wqkvT + 768 * 256;

    prep_weights<<<dim3(1024), dim3(256), 0, stream>>>(wqkv, wproj, wqkvT, wprojT);
    winattn_fused<<<dim3(2048), dim3(512), 0, stream>>>(x, bqkv, bproj, wqkvT, wprojT, out);
}

// Round 4
// 189.701 us; speedup vs baseline: 1.8206x; 1.8206x over previous
//
#include <hip/hip_runtime.h>
#include <hip/hip_bf16.h>

typedef __attribute__((ext_vector_type(8))) short bf16x8;
typedef __attribute__((ext_vector_type(4))) float f32x4;

#define MFMA32(A,B,C) __builtin_amdgcn_mfma_f32_16x16x32_bf16(A,B,C,0,0,0)

__device__ __forceinline__ short f2bf(float f) {
    union { float f; unsigned u; } v; v.f = f;
    unsigned r = v.u + 0x7FFFu + ((v.u >> 16) & 1u);
    return (short)(r >> 16);
}

// One-time: transpose+convert weights to bf16.  wqkvT[768][256], wprojT[256][256]
__global__ void prep_weights(const float* __restrict__ wqkv,
                             const float* __restrict__ wproj,
                             short* __restrict__ wqkvT,
                             short* __restrict__ wprojT) {
    const int n = blockIdx.x, k = threadIdx.x;
    if (n < 768) wqkvT[n * 256 + k] = f2bf(wqkv[k * 768 + n]);
    else         wprojT[(n - 768) * 256 + k] = f2bf(wproj[k * 256 + (n - 768)]);
}

// swapped QKV pass: D[ch][token] = W . xw^T ; packed acc -> K=32 frag of [token][ch] (ch-halves
// in low/high 4 elems: ch c = h*16 + l4*4 + rg  <->  k' = l4*8 + h*4 + rg)
#define QK_PASS(WPTR, BOFF, SCALE, FOUT)                                                   \
  {                                                                                        \
    f32x4 acc[2][4];                                                                       \
    _Pragma("unroll") for (int h=0;h<2;++h)                                                \
      _Pragma("unroll") for (int t=0;t<4;++t) acc[h][t]=(f32x4){0.f,0.f,0.f,0.f};          \
    _Pragma("unroll") for (int kk=0;kk<8;++kk) {                                           \
      bf16x8 xf[4];                                                                        \
      _Pragma("unroll") for (int t=0;t<4;++t) {                                            \
        const int row = t*16 + l15;                                                        \
        xf[t] = *(const bf16x8*)(smem + row*512 + (((kk<<6)+(l4<<4)) ^ ((row&7)<<4)));     \
      }                                                                                    \
      _Pragma("unroll") for (int h=0;h<2;++h) {                                            \
        bf16x8 wf = *(const bf16x8*)((WPTR) + (h*16+l15)*256 + (kk<<5) + (l4<<3));         \
        _Pragma("unroll") for (int t=0;t<4;++t)                                            \
          acc[h][t] = MFMA32(wf, xf[t], acc[h][t]);                                        \
      }                                                                                    \
    }                                                                                      \
    _Pragma("unroll") for (int h=0;h<2;++h) {                                              \
      f32x4 bias = *(const f32x4*)(bqkv + (BOFF) + h*16 + (l4<<2));                        \
      _Pragma("unroll") for (int t=0;t<4;++t)                                               \
        _Pragma("unroll") for (int rg=0;rg<4;++rg)                                         \
          FOUT[t][h*4+rg] = f2bf((acc[h][t][rg] + bias[rg]) * (SCALE));                    \
    }                                                                                      \
  }

__launch_bounds__(512, 2)
__global__ void winattn_fused(const float* __restrict__ x,
                              const float* __restrict__ bqkv,
                              const float* __restrict__ bproj,
                              const short* __restrict__ wqkvT,
                              const short* __restrict__ wprojT,
                              float* __restrict__ out) {
    __shared__ char smem[65536];
    char* cbuf = smem + 32768;
    const int tid = threadIdx.x;
    const int wid = blockIdx.x;
    const int b  = wid >> 6;
    const int wh = (wid >> 3) & 7;
    const int ww = wid & 7;

    // ---------- Phase 1: stage rolled window -> LDS bf16 [64 rows][512B], XOR-swizzled ----------
    {
        const int r  = tid >> 3;
        const int cb = (tid & 7) << 5;
        if (r < 49) {
            const int i = r / 7, j = r - i * 7;
            int h  = wh * 7 + i + 3; if (h  >= 56) h  -= 56;
            int wc = ww * 7 + j + 3; if (wc >= 56) wc -= 56;
            const float* src = x + (((size_t)(b * 56 + h)) * 56 + wc) * 256 + cb;
            #pragma unroll
            for (int c = 0; c < 4; ++c) {
                f32x4 f0 = *(const f32x4*)(src + c * 8);
                f32x4 f1 = *(const f32x4*)(src + c * 8 + 4);
                bf16x8 o;
                #pragma unroll
                for (int q = 0; q < 4; ++q) { o[q] = f2bf(f0[q]); o[q + 4] = f2bf(f1[q]); }
                const int colbyte = (cb + c * 8) * 2;
                *(bf16x8*)(smem + r * 512 + (colbyte ^ ((r & 7) << 4))) = o;
            }
        } else {
            bf16x8 z;
            #pragma unroll
            for (int q = 0; q < 8; ++q) z[q] = 0;
            #pragma unroll
            for (int c = 0; c < 4; ++c) {
                const int colbyte = (cb + c * 8) * 2;
                *(bf16x8*)(smem + r * 512 + (colbyte ^ ((r & 7) << 4))) = z;
            }
        }
    }
    __syncthreads();

    const int wv  = tid >> 6;     // wave = head
    const int l   = tid & 63;
    const int l15 = l & 15;
    const int l4  = l >> 4;

    const short* wq  = wqkvT + ((wv << 5) << 8);
    const short* wk  = wq + (256 << 8);
    const short* wvv = wq + (512 << 8);

    // ---------- Phase 2a: q,k (swapped) — packed K=32 fragments, zero LDS round-trip ----------
    bf16x8 qp[4], kp[4];            // [token-tile], elems = packed ch (2 halves x 4)
    QK_PASS(wq, (wv << 5), 0.17677669529663687f, qp)
    QK_PASS(wk, 256 + (wv << 5), 1.0f, kp)

    // ---------- Phase 3a+3b fused per q-tile: S' column -> softmax -> packed P frag ----------
    // Slice sQ[t] (16 regs) dies each iteration; peak pressure stays ~95 regs.
    bf16x8 pp[4][2];                // [q-tile][kt-tile-pair], elems: low4 = even tile, high4 = odd
    #pragma unroll
    for (int qt = 0; qt < 4; ++qt) {
        f32x4 sQ[4];
        #pragma unroll
        for (int t = 0; t < 4; ++t) sQ[t] = (f32x4){0.f, 0.f, 0.f, 0.f};
        #pragma unroll
        for (int t = 0; t < 4; ++t)
            sQ[t] = MFMA32(kp[t], qp[qt], sQ[t]);   // D[kt][q]: col=l15=q, row=l4*4+rg=kt

        float m = -1e30f;
        #pragma unroll
        for (int t = 0; t < 4; ++t)
            #pragma unroll
            for (int rg = 0; rg < 4; ++rg) {
                const bool valid = (t < 3) || ((l4 | rg) == 0);   // kt < 49
                float v0 = valid ? sQ[t][rg] : -1e30f;
                sQ[t][rg] = v0;
                m = fmaxf(m, v0);
            }
        m = fmaxf(m, __shfl_xor(m, 16));
        m = fmaxf(m, __shfl_xor(m, 32));
        float s = 0.f;
        #pragma unroll
        for (int t = 0; t < 4; ++t)
            #pragma unroll
            for (int rg = 0; rg < 4; ++rg) {
                float e = __expf(sQ[t][rg] - m);    // masked entries underflow to 0
                sQ[t][rg] = e;
                s += e;
            }
        s += __shfl_xor(s, 16);
        s += __shfl_xor(s, 32);
        const float inv = 1.f / s;
        #pragma unroll
        for (int t = 0; t < 4; ++t)
            #pragma unroll
            for (int rg = 0; rg < 4; ++rg)
                pp[qt][t >> 1][(t & 1) * 4 + rg] = f2bf(sQ[t][rg] * inv);
    }

    // ---------- Phase 2b: v (unswapped) — packed V^T B-fragments directly ----------
    bf16x8 vp[2][2];                // [kt-tile-pair][ch-half]
    {
        f32x4 acc[4][2];
        #pragma unroll
        for (int t = 0; t < 4; ++t)
            #pragma unroll
            for (int h = 0; h < 2; ++h) acc[t][h] = (f32x4){0.f, 0.f, 0.f, 0.f};
        #pragma unroll
        for (int kk = 0; kk < 8; ++kk) {
            bf16x8 xf[4];
            #pragma unroll
            for (int t = 0; t < 4; ++t) {
                const int row = t * 16 + l15;
                xf[t] = *(const bf16x8*)(smem + row * 512 + (((kk << 6) + (l4 << 4)) ^ ((row & 7) << 4)));
            }
            #pragma unroll
            for (int h = 0; h < 2; ++h) {
                bf16x8 wf = *(const bf16x8*)(wvv + (h * 16 + l15) * 256 + (kk << 5) + (l4 << 3));
                #pragma unroll
                for (int t = 0; t < 4; ++t)
                    acc[t][h] = MFMA32(xf[t], wf, acc[t][h]);
            }
        }
        #pragma unroll
        for (int h = 0; h < 2; ++h) {
            const float bias = bqkv[512 + (wv << 5) + h * 16 + l15];
            #pragma unroll
            for (int t = 0; t < 4; ++t)
                #pragma unroll
                for (int rg = 0; rg < 4; ++rg)
                    vp[t >> 1][h][(t & 1) * 4 + rg] = f2bf(acc[t][h][rg] + bias);
        }
    }

    // ---------- Phase 3c: O = P.V — 16 MFMA32 ----------
    f32x4 o[4][2];                  // [q-tile][ch-half]
    #pragma unroll
    for (int qt = 0; qt < 4; ++qt)
        #pragma unroll
        for (int h = 0; h < 2; ++h) o[qt][h] = (f32x4){0.f, 0.f, 0.f, 0.f};
    #pragma unroll
    for (int tp = 0; tp < 2; ++tp)
        #pragma unroll
        for (int h = 0; h < 2; ++h)
            #pragma unroll
            for (int qt = 0; qt < 4; ++qt)
                o[qt][h] = MFMA32(pp[qt][tp], vp[tp][h], o[qt][h]);

    // heads concat -> cbuf (swizzled [64][512B])
    #pragma unroll
    for (int qt = 0; qt < 4; ++qt)
        #pragma unroll
        for (int h = 0; h < 2; ++h)
            #pragma unroll
            for (int rg = 0; rg < 4; ++rg) {
                const int row = qt * 16 + (l4 << 2) + rg;
                const int col = (wv << 5) + (h << 4) + l15;
                *(short*)(cbuf + row * 512 + ((col * 2) ^ ((row & 7) << 4))) = f2bf(o[qt][h][rg]);
            }
    __syncthreads();

    // ---------- Phase 4: proj GEMM + bias + scatter to un-rolled positions ----------
    f32x4 po[2][4];
    #pragma unroll
    for (int c = 0; c < 2; ++c)
        #pragma unroll
        for (int r = 0; r < 4; ++r) po[c][r] = (f32x4){0.f, 0.f, 0.f, 0.f};

    #pragma unroll
    for (int kk = 0; kk < 8; ++kk) {
        bf16x8 a[4];
        #pragma unroll
        for (int rt = 0; rt < 4; ++rt) {
            const int row = rt * 16 + l15;
            a[rt] = *(const bf16x8*)(cbuf + row * 512 + (((kk << 6) + (l4 << 4)) ^ ((row & 7) << 4)));
        }
        #pragma unroll
        for (int ct = 0; ct < 2; ++ct) {
            const short* bp = wprojT + (((wv << 5) + (ct << 4) + l15) << 8) + (kk << 5) + (l4 << 3);
            bf16x8 bfr = *(const bf16x8*)bp;
            #pragma unroll
            for (int rt = 0; rt < 4; ++rt)
                po[ct][rt] = MFMA32(a[rt], bfr, po[ct][rt]);
        }
    }

    #pragma unroll
    for (int ct = 0; ct < 2; ++ct) {
        const int col = (wv << 5) + (ct << 4) + l15;
        const float bias = bproj[col];
        #pragma unroll
        for (int rt = 0; rt < 4; ++rt) {
            #pragma unroll
            for (int rg = 0; rg < 4; ++rg) {
                const int row = rt * 16 + (l4 << 2) + rg;
                if (row < 49) {
                    const int i = row / 7, j = row - i * 7;
                    int h  = wh * 7 + i + 3; if (h  >= 56) h  -= 56;
                    int wc = ww * 7 + j + 3; if (wc >= 56) wc -= 56;
                    out[(((size_t)(b * 56 + h)) * 56 + wc) * 256 + col] = po[ct][rt][rg] + bias;
                }
            }
        }
    }
}

extern "C" void kernel_launch(void* const* d_in, const int* in_sizes, int n_in,
                              void* d_out, int out_size, void* d_ws, size_t ws_size,
                              hipStream_t stream) {
    const float* x     = (const float*)d_in[0];
    const float* wqkv  = (const float*)d_in[1];
    const float* bqkv  = (const float*)d_in[2];
    const float* wproj = (const float*)d_in[3];
    const float* bproj = (const float*)d_in[4];
    float* out = (float*)d_out;

    short* wqkvT  = (short*)d_ws;
    short* wprojT = wqkvT + 768 * 256;

    prep_weights<<<dim3(1024), dim3(256), 0, stream>>>(wqkv, wproj, wqkvT, wprojT);
    winattn_fused<<<dim3(2048), dim3(512), 0, stream>>>(x, bqkv, bproj, wqkvT, wprojT, out);
}